// Round 5
// baseline (466.416 us; speedup 1.0000x reference)
//
#include <hip/hip_runtime.h>

#define BS 4096
#define IN_DIM 2048
#define NFFT 16384
#define TOTAL_D 129
#define SLACK 64
#define KF 128          // GEMM feature count (DC handled separately)

#define INV_N_SQRT 0.0078125f            // 1/128
#define SC_PAIR 0.011048543456039804f    // sqrt(2)/128
#define TWO_PI_OVER_N 3.8349519697141029e-4f

typedef __attribute__((ext_vector_type(8))) short bf16x8;
typedef __attribute__((ext_vector_type(4))) float f32x4;

__device__ __forceinline__ ushort f2bf(float f) {
    union { float f; unsigned u; } v; v.f = f;
    unsigned r = v.u + 0x7fffu + ((v.u >> 16) & 1u);   // round-nearest-even
    return (ushort)(r >> 16);
}

// ---------------------------------------------------------------------------
// Basis: Bb[t][k] bf16, k in [0,128). k<64: pure cos/sin of f=k/2+1 (exact
// integer phase); k>=64: Ws[t][k-64]. Scales folded into hs features.
// ---------------------------------------------------------------------------
__global__ __launch_bounds__(256) void k_basis(const float* __restrict__ Ws,
                                               ushort* __restrict__ Bb) {
    int idx = blockIdx.x * 256 + threadIdx.x;    // 16384*16 work items
    int t = idx >> 4, g = idx & 15;
    ushort r[8];
    if (g < 8) {
#pragma unroll
        for (int p = 0; p < 4; ++p) {
            int f = 4 * g + p + 1;                       // 1..32
            int phase = (f * t) & (NFFT - 1);
            float ang = (float)phase * TWO_PI_OVER_N;
            float sv, cv;
            __sincosf(ang, &sv, &cv);
            r[2 * p] = f2bf(cv);
            r[2 * p + 1] = f2bf(sv);
        }
    } else {
        const float* w = &Ws[(size_t)t * SLACK + (g - 8) * 8];
        float4 w0 = *(const float4*)w;
        float4 w1 = *(const float4*)(w + 4);
        r[0] = f2bf(w0.x); r[1] = f2bf(w0.y); r[2] = f2bf(w0.z); r[3] = f2bf(w0.w);
        r[4] = f2bf(w1.x); r[5] = f2bf(w1.y); r[6] = f2bf(w1.z); r[7] = f2bf(w1.w);
    }
    ushort4 lo = {r[0], r[1], r[2], r[3]};
    ushort4 hi = {r[4], r[5], r[6], r[7]};
    ushort* dst = &Bb[(size_t)t * KF + g * 8];
    *(ushort4*)dst = lo;
    *(ushort4*)(dst + 4) = hi;
}

// ---------------------------------------------------------------------------
// FUSED proj+finalize: h[b][c] = sum_k x[b][k]*W[c][k] + bias, full K=2048
// (no split-K, no h_part round-trip: saves 42 MB of HBM traffic).
// Tile M=32 x N=160, BK=64, 128 blocks. Waves 2x2: wm = b-half (16 rows),
// wn = c-half (80 cols, 5 frags). Epilogue applies bias + scales, writes
// dc0 (c==0) and bf16 hs (c=1..128) directly.
// ---------------------------------------------------------------------------
__global__ __launch_bounds__(256) void k_projfin(const float* __restrict__ x,
                                                 const float* __restrict__ W,
                                                 const float* __restrict__ bvec,
                                                 float* __restrict__ dc0,
                                                 ushort* __restrict__ hs) {
    __shared__ ushort As[32 * 72];    // x tile  [32][64], stride 72: <=2-way banks
    __shared__ ushort Bs[160 * 72];   // W tile [160][64]
    const int tid = threadIdx.x;
    const int lane = tid & 63, wave = tid >> 6;
    const int quad = lane >> 4, m = lane & 15;
    const int wm = wave & 1, wn = wave >> 1;
    const int r0 = blockIdx.x * 32;

    f32x4 acc[5];
#pragma unroll
    for (int j = 0; j < 5; ++j) acc[j] = 0.f;

    for (int kb = 0; kb < IN_DIM; kb += 64) {
        // stage x tile 32x64 (fp32 -> bf16): 512 float4 chunks, 2 per thread
#pragma unroll
        for (int it = 0; it < 2; ++it) {
            int v = tid + it * 256;
            int row = v >> 4, c = v & 15;
            float4 xv = *(const float4*)&x[(size_t)(r0 + row) * IN_DIM + kb + c * 4];
            ushort4 o = {f2bf(xv.x), f2bf(xv.y), f2bf(xv.z), f2bf(xv.w)};
            *(ushort4*)&As[row * 72 + c * 4] = o;
        }
        // stage W tile 160x64 (rows >=129 clamped; cols discarded in epilogue)
#pragma unroll
        for (int it = 0; it < 10; ++it) {
            int v = tid + it * 256;
            int row = v >> 4, c = v & 15;
            int rw = row < TOTAL_D ? row : TOTAL_D - 1;
            float4 wv = *(const float4*)&W[(size_t)rw * IN_DIM + kb + c * 4];
            ushort4 o = {f2bf(wv.x), f2bf(wv.y), f2bf(wv.z), f2bf(wv.w)};
            *(ushort4*)&Bs[row * 72 + c * 4] = o;
        }
        __syncthreads();
#pragma unroll
        for (int ks = 0; ks < 2; ++ks) {
            bf16x8 af = *(const bf16x8*)&As[(wm * 16 + m) * 72 + ks * 32 + quad * 8];
            bf16x8 bfr[5];
#pragma unroll
            for (int j = 0; j < 5; ++j)
                bfr[j] = *(const bf16x8*)&Bs[(wn * 80 + j * 16 + m) * 72 + ks * 32 + quad * 8];
#pragma unroll
            for (int j = 0; j < 5; ++j)
                acc[j] = __builtin_amdgcn_mfma_f32_16x16x32_bf16(af, bfr[j], acc[j], 0, 0, 0);
        }
        __syncthreads();
    }
    // epilogue: C/D layout col=lane&15 (c-dim), row=quad*4+reg (b-dim)
#pragma unroll
    for (int j = 0; j < 5; ++j) {
        int c = wn * 80 + j * 16 + m;
        if (c >= TOTAL_D) continue;
        float bias = bvec[c];
#pragma unroll
        for (int reg = 0; reg < 4; ++reg) {
            int row = r0 + wm * 16 + quad * 4 + reg;
            float val = acc[j][reg] + bias;
            if (c == 0) {
                dc0[row] = val * INV_N_SQRT;
            } else {
                int k = c - 1;
                float sc = (k < 64) ? SC_PAIR : 1.f;
                hs[(size_t)row * KF + k] = f2bf(val * sc);
            }
        }
    }
}

// ---------------------------------------------------------------------------
// Main GEMM: out[b][t] = dc0[b] + sum_k hs[b][k]*Bb[t][k]
// EXACT r0 structure (proven 335.6 us): one-shot LDS stage, XOR swizzle,
// plain stores, natural dispatch (bx&7 already gives per-XCD Bb affinity).
// OPERAND-SWAPPED: MFMA-M = t, MFMA-N = b; each acc f32x4 is a direct
// dwordx4 store, 4 quads of a quarter-wave complete a 64B line.
// ---------------------------------------------------------------------------
__global__ __launch_bounds__(256, 2) void k_main(const ushort* __restrict__ hs,
                                                 const float* __restrict__ dc0,
                                                 const ushort* __restrict__ Bb,
                                                 float* __restrict__ out) {
    __shared__ ushort As[128 * 128];   // basis tile [t_local][k], swizzled
    __shared__ ushort Bs[128 * 128];   // hs tile    [b_local][k], swizzled
    const int tid = threadIdx.x;
    const int lane = tid & 63, wave = tid >> 6;
    const int quad = lane >> 4, m = lane & 15;
    const int wm = wave & 1, wn = wave >> 1;   // wm -> t-half, wn -> b-half
    const int t0 = blockIdx.x * 128;
    const int b0 = blockIdx.y * 128;

    // stage basis (A) and hs (B), XOR-swizzled so frag reads are <=2-way
#pragma unroll
    for (int it = 0; it < 8; ++it) {
        int v = tid + it * 256;
        int row = v >> 4, g = v & 15;
        uint4 d = *(const uint4*)&Bb[((size_t)(t0 + row) << 7) + g * 8];
        *(uint4*)&As[(row << 7) + ((g ^ (row & 7)) * 8)] = d;
    }
#pragma unroll
    for (int it = 0; it < 8; ++it) {
        int v = tid + it * 256;
        int row = v >> 4, g = v & 15;
        uint4 d = *(const uint4*)&hs[((size_t)(b0 + row) << 7) + g * 8];
        *(uint4*)&Bs[(row << 7) + ((g ^ (row & 7)) * 8)] = d;
    }

    // DC term as C-init: per-lane scalar broadcast of dc0[b]
    f32x4 acc[4][4];
#pragma unroll
    for (int j = 0; j < 4; ++j) {
        float d = dc0[b0 + wn * 64 + j * 16 + m];
#pragma unroll
        for (int i = 0; i < 4; ++i) acc[i][j] = d;
    }
    __syncthreads();

#pragma unroll
    for (int ks = 0; ks < 4; ++ks) {
        bf16x8 af[4], bfr[4];
#pragma unroll
        for (int i = 0; i < 4; ++i) {
            int row = wm * 64 + i * 16 + m;
            af[i] = *(const bf16x8*)&As[(row << 7) + (((ks * 4 + quad) ^ (row & 7)) * 8)];
        }
#pragma unroll
        for (int j = 0; j < 4; ++j) {
            int row = wn * 64 + j * 16 + m;
            bfr[j] = *(const bf16x8*)&Bs[(row << 7) + (((ks * 4 + quad) ^ (row & 7)) * 8)];
        }
#pragma unroll
        for (int i = 0; i < 4; ++i)
#pragma unroll
            for (int j = 0; j < 4; ++j)
                acc[i][j] = __builtin_amdgcn_mfma_f32_16x16x32_bf16(af[i], bfr[j], acc[i][j], 0, 0, 0);
    }

    // epilogue: 16 dwordx4 stores per thread, quads complete 64B lines
#pragma unroll
    for (int j = 0; j < 4; ++j) {
        size_t rowb = (size_t)(b0 + wn * 64 + j * 16 + m);
        float* orow = out + rowb * NFFT + t0 + wm * 64 + quad * 4;
#pragma unroll
        for (int i = 0; i < 4; ++i)
            *(f32x4*)&orow[i * 16] = acc[i][j];
    }
}

extern "C" void kernel_launch(void* const* d_in, const int* in_sizes, int n_in,
                              void* d_out, int out_size, void* d_ws, size_t ws_size,
                              hipStream_t stream) {
    const float* x   = (const float*)d_in[0];
    const float* W   = (const float*)d_in[1];
    const float* b   = (const float*)d_in[2];
    const float* Wsl = (const float*)d_in[3];
    float* out = (float*)d_out;

    char* ws = (char*)d_ws;
    ushort* Bb  = (ushort*)ws;                          // 16384*128*2 = 4.0 MB
    ushort* hs  = (ushort*)(ws + 4194304);              // 4096*128*2  = 1.0 MB
    float*  dc0 = (float*)(ws + 5242880);               // 4096*4      = 16 KB

    k_basis<<<NFFT * 16 / 256, 256, 0, stream>>>(Wsl, Bb);
    k_projfin<<<BS / 32, 256, 0, stream>>>(x, W, b, dc0, hs);
    k_main<<<dim3(NFFT / 128, BS / 128), 256, 0, stream>>>(hs, dc0, Bb, out);
}